// Round 1
// baseline (12029.933 us; speedup 1.0000x reference)
//
#include <hip/hip_runtime.h>
#include <hip/hip_fp16.h>

// TKANCell B=64,T=2048,D=128,U=128,NS=3 — fp32 in/out.
// 64 independent chains (tf.reshape routes sub-row r=3b'+j to batch b'=r/3).
// R6 theory: per-step cost dominated by L2 weight re-streaming (~786KB/step:
// 393KB fp16 Wr/Wh/Dw/Aw + ~393KB fp32 Wk/Wx amortized via chunk phase).
// Fix: (1) precompute gx/ax for ALL (chain,t) in a parallel pre-pass (gax_pre,
// 4096 blocks, 8x-ti register reuse of Wk/Wx) into workspace; (2) serial kernel
// tkan2 drops the chunk phase, caches Wh+Dw slices (up to 2 each) in the freed
// LDS, streams only Wr+Aw (192KB/step fp16) + 1.5KB gax row per step.
// Gated on ws_size >= ~192.4MiB; falls back to the verified WS/NOWS kernels.

#define TT 2048
#define BB 64
#define TC 32

typedef unsigned int u32;

__device__ __forceinline__ float sigf(float x) { return 1.f / (1.f + __expf(-x)); }
__device__ __forceinline__ float tanh_(float x) { return 2.f / (1.f + __expf(-2.f * x)) - 1.f; }
__device__ __forceinline__ float2 h2f2(u32 u) {
    __half2 h = *(__half2*)&u;
    return __half22float2(h);
}

// acc += W[k][quad*4 .. +3] * v[k] over k in [k0,k0+kn).
// idxBase/stride in quad units (uint2 for fp16, float4 for fp32 — same index).
template <bool WS>
__device__ __forceinline__ void dotq(const void* W, int idxBase, int stride,
                                     const float* __restrict__ v, int k0, int kn,
                                     float4& acc) {
    if (WS) {
        const uint2* Wp = (const uint2*)W;
#pragma unroll 8
        for (int k = k0; k < k0 + kn; ++k) {
            uint2 w = Wp[idxBase + k * stride];
            float2 lo = h2f2(w.x), hi = h2f2(w.y);
            float xv = v[k];
            acc.x += lo.x * xv; acc.y += lo.y * xv;
            acc.z += hi.x * xv; acc.w += hi.y * xv;
        }
    } else {
        const float4* Wp = (const float4*)W;
#pragma unroll 8
        for (int k = k0; k < k0 + kn; ++k) {
            float4 w = Wp[idxBase + k * stride];
            float xv = v[k];
            acc.x += w.x * xv; acc.y += w.y * xv;
            acc.z += w.z * xv; acc.w += w.w * xv;
        }
    }
}

// fp16 dot, typed pointer so address space (global vs LDS) is inferred per call
// site after inlining.
__device__ __forceinline__ void dotq_h(const uint2* Wp, int idxBase, int stride,
                                       const float* __restrict__ v, int k0, int kn,
                                       float4& acc) {
#pragma unroll 8
    for (int k = k0; k < k0 + kn; ++k) {
        uint2 w = Wp[idxBase + k * stride];
        float2 lo = h2f2(w.x), hi = h2f2(w.y);
        float xv = v[k];
        acc.x += lo.x * xv; acc.y += lo.y * xv;
        acc.z += hi.x * xv; acc.w += hi.y * xv;
    }
}

// fp16 copy of Wr|Wh|Dw|Aw (each 49152 elems, layout preserved).
__global__ __launch_bounds__(512) void convert_w(
    const float* __restrict__ Wr, const float* __restrict__ Wh,
    const float* __restrict__ Dw, const float* __restrict__ Aw,
    __half* __restrict__ dst) {
    int g = blockIdx.x * 512 + threadIdx.x;  // 0..196607
    int seg = g / 49152, idx = g % 49152;
    const float* src = (seg == 0) ? Wr : (seg == 1) ? Wh : (seg == 2) ? Dw : Aw;
    dst[g] = __float2half(src[idx]);
}

// ===== WS2 pre-pass: gax[bp][t][768] fp16 = [x@Wk (384) | x@Wx slices (384)].
// Grid (64 chains, 64 chunks of 32 steps), 384 threads. Each thread does 2
// tasks; each task = one quad r x 8 consecutive ti, so each weight float4 is
// loaded once and reused 8x in registers (8x less L1/L2 traffic than chunk
// phase). fp32 accumulation order identical to the verified chunk phase.
__global__ __launch_bounds__(384, 3) void gax_pre(
    const float* __restrict__ xg, const float* __restrict__ Wk,
    const float* __restrict__ Wx, __half* __restrict__ gax) {
    const int bp = blockIdx.x, tc = blockIdx.y, tid = threadIdx.x;
    const int t0 = tc * 32;
    __shared__ __align__(16) float xCt[4][128][32];  // 64KB, [v][k][ti]

    for (int f = tid; f < 4096; f += 384) {
        int v_ = f >> 10, ti = (f >> 5) & 31, kq = f & 31;
        int row = (v_ == 0) ? bp : ((3 * bp + (v_ - 1)) & 63);
        float4 w = ((const float4*)(xg + ((size_t)row * TT + t0 + ti) * 128))[kq];
        xCt[v_][4 * kq + 0][ti] = w.x;
        xCt[v_][4 * kq + 1][ti] = w.y;
        xCt[v_][4 * kq + 2][ti] = w.z;
        xCt[v_][4 * kq + 3][ti] = w.w;
    }
    __syncthreads();

    const float4* Wk4 = (const float4*)Wk;
    const float4* Wx4 = (const float4*)Wx;

    for (int task = tid; task < 768; task += 384) {
        int grp = task / 192, r = task % 192;
        int ti0 = grp * 8;
        const float4* Wp;
        int base, stride, v;
        if (r < 96) {
            Wp = Wk4; base = r; stride = 96; v = 0;
        } else {
            int jq = r - 96, j = jq >> 5, qi = jq & 31;
            int nj = (3 * bp + j) >> 6;
            Wp = Wx4; base = nj * 4096 + qi; stride = 32; v = 1 + j;
        }
        float4 acc[8];
#pragma unroll
        for (int i = 0; i < 8; ++i) acc[i] = make_float4(0.f, 0.f, 0.f, 0.f);
#pragma unroll 4
        for (int k = 0; k < 128; ++k) {
            float4 w = Wp[base + k * stride];
            float4 xa = *(const float4*)&xCt[v][k][ti0];
            float4 xb = *(const float4*)&xCt[v][k][ti0 + 4];
#pragma unroll
            for (int i = 0; i < 4; ++i) {
                float xv = (&xa.x)[i];
                acc[i].x += w.x * xv; acc[i].y += w.y * xv;
                acc[i].z += w.z * xv; acc[i].w += w.w * xv;
            }
#pragma unroll
            for (int i = 0; i < 4; ++i) {
                float xv = (&xb.x)[i];
                acc[4 + i].x += w.x * xv; acc[4 + i].y += w.y * xv;
                acc[4 + i].z += w.z * xv; acc[4 + i].w += w.w * xv;
            }
        }
#pragma unroll
        for (int i = 0; i < 8; ++i) {
            size_t off = ((size_t)bp * TT + (size_t)(t0 + ti0 + i)) * 768 + 4 * r;
            __half2 lo = __floats2half2_rn(acc[i].x, acc[i].y);
            __half2 hi = __floats2half2_rn(acc[i].z, acc[i].w);
            uint2 pk = make_uint2(*(u32*)&lo, *(u32*)&hi);
            *(uint2*)(gax + off) = pk;
        }
    }
}

// ===== WS2 serial kernel: no chunk phase; Wh/Dw slices resident in LDS
// (nslice 1 for 62/64 blocks, 2 for bp=21,42); Wr/Aw streamed fp16 from L2;
// gax row (1.5KB) loaded at step start, latency hidden under S1 dots.
__global__ __launch_bounds__(512, 1) void tkan2(
    const float* __restrict__ bias, const float* __restrict__ stk,
    const float* __restrict__ Db, const float* __restrict__ Ab,
    const __half* __restrict__ wt, float* __restrict__ outp) {
    const int bp = blockIdx.x, tid = threadIdx.x;

    __shared__ uint2 WhL[8192];  // up to 2 slices x 4096 uint2 (64KB)
    __shared__ uint2 DwL[8192];  // 64KB
    __shared__ float hS[128], cS[128], tcS[128];
    __shared__ float sS[384], aS[384], pS[384], gS[384];
    __shared__ float part1[384][4], part2[192][4], part3[256][4];
    __shared__ float biasL[384], stkj[3][2][128], DbL[3][128], AbL[128];

    const int nj0 = (3 * bp) >> 6;
    const int nslice = ((3 * bp + 2) >> 6) - nj0 + 1;  // 1 or 2

    if (tid < 128) { hS[tid] = 0.f; cS[tid] = 0.f; AbL[tid] = Ab[tid]; }
    if (tid >= 128 && tid < 512) {
        int q = tid - 128;
        sS[q] = 0.f;
        biasL[q] = bias[q];
    }
    {
        int j = tid >> 7, o = tid & 127;
        if (j < 3) {
            int nj = (3 * bp + j) >> 6;
            stkj[j][0][o] = stk[nj * 256 + o];
            stkj[j][1][o] = stk[nj * 256 + 128 + o];
            DbL[j][o] = Db[nj * 128 + o];
        }
    }
    const uint2* wtWh = (const uint2*)(wt + 49152);
    const uint2* wtDw = (const uint2*)(wt + 98304);
    for (int i = tid; i < nslice * 4096; i += 512) {
        int s = i >> 12, idx = i & 4095;
        WhL[i] = wtWh[(nj0 + s) * 4096 + idx];
        DwL[i] = wtDw[(nj0 + s) * 4096 + idx];
    }
    __syncthreads();

    const uint2* wWr = (const uint2*)wt;             // row stride 96 quads
    const uint2* wAw = (const uint2*)(wt + 147456);  // stride 32 quads
    const uint2* gaxRow = (const uint2*)(wt + 196608 + (size_t)bp * TT * 768 / 4 * 4);
    // (wt is __half*; 196608 + bp*2048*768 halfs; uint2 = 4 halfs)
    gaxRow = (const uint2*)(wt + 196608 + (size_t)bp * TT * 768);

    for (int t = 0; t < TT; ++t) {
        uint2 gv;
        if (tid < 192) gv = gaxRow[t * 192 + tid];  // issue early; used at S1r

        // ===== S1: Wr (h->gates, global fp16) + Wh (s->agg, LDS); K split 2
        if (tid < 384) {
            float4 acc = {0.f, 0.f, 0.f, 0.f};
            if (tid < 192) {
                int q = tid % 96, ks = tid / 96;
                dotq_h(wWr, q, 96, hS, ks * 64, 64, acc);
            } else {
                int t2 = tid - 192, jq = t2 % 96, ks = t2 / 96;
                int j = jq >> 5, qi = jq & 31;
                int sj = ((3 * bp + j) >> 6) - nj0;
                dotq_h(WhL, sj * 4096 + qi, 32, sS + j * 128, ks * 64, 64, acc);
            }
            *(float4*)&part1[tid][0] = acc;
        }
        __syncthreads();

        // ===== S1r: reduce + add gx/ax(+bias) -> gS, aS
        if (tid < 192) {
            if (tid < 96) {
                int q = tid;
                float4 a0 = *(float4*)&part1[q][0];
                float4 a1 = *(float4*)&part1[q + 96][0];
                float2 g0 = h2f2(gv.x), g1 = h2f2(gv.y);
                float4 r;
                r.x = a0.x + a1.x + g0.x + biasL[4 * q];
                r.y = a0.y + a1.y + g0.y + biasL[4 * q + 1];
                r.z = a0.z + a1.z + g1.x + biasL[4 * q + 2];
                r.w = a0.w + a1.w + g1.y + biasL[4 * q + 3];
                *(float4*)&gS[4 * q] = r;
            } else {
                int cq = tid - 96;
                float4 a0 = *(float4*)&part1[192 + cq][0];
                float4 a1 = *(float4*)&part1[288 + cq][0];
                float2 g0 = h2f2(gv.x), g1 = h2f2(gv.y);
                float4 r;
                r.x = a0.x + a1.x + g0.x;
                r.y = a0.y + a1.y + g0.y;
                r.z = a0.z + a1.z + g1.x;
                r.w = a0.w + a1.w + g1.y;
                *(float4*)&aS[4 * cq] = r;
            }
        }
        __syncthreads();

        // ===== S2: Dw partials (LDS, K split 2); c-update on threads 384+
        if (tid < 192) {
            int q = tid % 96, ks = tid / 96;
            int j = q >> 5, qi = q & 31;
            int sj = ((3 * bp + j) >> 6) - nj0;
            float4 acc = {0.f, 0.f, 0.f, 0.f};
            dotq_h(DwL, sj * 4096 + qi, 32, aS + j * 128, ks * 64, 64, acc);
            *(float4*)&part2[tid][0] = acc;
        } else if (tid >= 384) {
            int u = tid - 384;
            float gi = sigf(gS[u]);
            float gf = sigf(gS[128 + u]);
            float gc = sigf(gS[256 + u]);
            float cn = gf * cS[u] + gi * tanh_(gc);
            cS[u] = cn;
            tcS[u] = tanh_(cn);
        }
        __syncthreads();

        // ===== S2r: p = relu(. + Db)
        if (tid < 96) {
            int j = tid >> 5, o = (tid & 31) * 4;
            float4 a0 = *(float4*)&part2[tid][0];
            float4 a1 = *(float4*)&part2[tid + 96][0];
            float4 r;
            r.x = fmaxf(a0.x + a1.x + DbL[j][o], 0.f);
            r.y = fmaxf(a0.y + a1.y + DbL[j][o + 1], 0.f);
            r.z = fmaxf(a0.z + a1.z + DbL[j][o + 2], 0.f);
            r.w = fmaxf(a0.w + a1.w + DbL[j][o + 3], 0.f);
            *(float4*)&pS[4 * tid] = r;
        }
        __syncthreads();

        // ===== S3: Aw partials (global fp16, 32 quads x K-split 8); s-update
        if (tid < 256) {
            int q = tid & 31, ks = tid >> 5;
            float4 acc = {0.f, 0.f, 0.f, 0.f};
            dotq_h(wAw, q, 32, pS, ks * 48, 48, acc);
            *(float4*)&part3[tid][0] = acc;
        } else if (tid < 384) {
            int e = tid - 256;
#pragma unroll
            for (int j = 0; j < 3; ++j) {
                int q = j * 128 + e;
                sS[q] = stkj[j][0][e] * pS[q] + stkj[j][1][e] * sS[q];
            }
        }
        __syncthreads();

        // ===== S3r: finalize h, write out
        if (tid < 128) {
            int u = tid;
            float y = AbL[u];
#pragma unroll
            for (int ks = 0; ks < 8; ++ks) y += part3[ks * 32 + (u >> 2)][u & 3];
            float hn = sigf(y) * tcS[u];
            hS[u] = hn;
            outp[((size_t)bp * TT + t) * 128 + u] = hn;
        }
        __syncthreads();
    }
}

// ===== Verified fallback (unchanged): chunk-phase kernel =====
template <bool WS>
__global__ __launch_bounds__(512, 1) void tkan(
    const float* __restrict__ xg, const float* __restrict__ Wk,
    const float* __restrict__ Wr, const float* __restrict__ bias,
    const float* __restrict__ Wx, const float* __restrict__ Wh,
    const float* __restrict__ stk, const float* __restrict__ Dw,
    const float* __restrict__ Db, const float* __restrict__ Aw,
    const float* __restrict__ Ab, const __half* __restrict__ wt,
    float* __restrict__ outp) {
    const int bp = blockIdx.x, tid = threadIdx.x;

    __shared__ float xC[4][TC][128];          // 64KB chunk x rows
    __shared__ __half gxL[TC][384];           // 24KB x@Wk per chunk
    __shared__ __half axL[TC][384];           // 24KB x@Wx per chunk
    __shared__ float hS[128], cS[128], tcS[128];
    __shared__ float sS[384], aS[384], pS[384], gS[384];
    __shared__ float part1[384][4], part2[192][4], part3[256][4];
    __shared__ float biasL[384], stkj[3][2][128], DbL[3][128], AbL[128];
    __shared__ float dummy[WS ? 4 : 4096];    // LDS_Block_Size marker

    // ---- init
    if (tid < 128) { hS[tid] = 0.f; cS[tid] = 0.f; AbL[tid] = Ab[tid]; }
    if (tid >= 128 && tid < 512) {
        int q = tid - 128;
        sS[q] = 0.f;
        biasL[q] = bias[q];
    }
    {
        int j = tid >> 7, o = tid & 127;
        if (j < 3) {
            int nj = (3 * bp + j) >> 6;
            stkj[j][0][o] = stk[nj * 256 + o];
            stkj[j][1][o] = stk[nj * 256 + 128 + o];
            DbL[j][o] = Db[nj * 128 + o];
        }
    }
    if (bias[0] > 1e30f) { dummy[tid & 3] = 1.f; }  // never true; keeps dummy alive
    __syncthreads();

    const float4* Wk4 = (const float4*)Wk;   // row stride 96 quads
    const float4* Wx4 = (const float4*)Wx;   // slice 4096 quads, stride 32
    const void* wWr = WS ? (const void*)(wt)          : (const void*)Wr;
    const void* wWh = WS ? (const void*)(wt + 49152)  : (const void*)Wh;
    const void* wDw = WS ? (const void*)(wt + 98304)  : (const void*)Dw;
    const void* wAw = WS ? (const void*)(wt + 147456) : (const void*)Aw;

    for (int t = 0; t < TT; ++t) {
        int tt = t & (TC - 1);
        if (tt == 0) {
            for (int f = tid; f < 4096; f += 512) {
                int v_ = f >> 10, ti = (f >> 5) & 31, kq = f & 31;
                int row = (v_ == 0) ? bp : ((3 * bp + (v_ - 1)) & 63);
                float4 w = ((const float4*)(xg + ((size_t)row * TT + t + ti) * 128))[kq];
                float* d = &xC[v_][ti][kq * 4];
                d[0] = w.x; d[1] = w.y; d[2] = w.z; d[3] = w.w;
            }
            __syncthreads();
            for (int ct = tid; ct < TC * 192; ct += 512) {
                int ti = ct / 192, r = ct % 192;
                float4 acc = {0.f, 0.f, 0.f, 0.f};
                if (r < 96) {
                    const float* v = xC[0][ti];
#pragma unroll 8
                    for (int k = 0; k < 128; ++k) {
                        float4 w = Wk4[k * 96 + r];
                        float xv = v[k];
                        acc.x += w.x * xv; acc.y += w.y * xv;
                        acc.z += w.z * xv; acc.w += w.w * xv;
                    }
                    int qout = r;
                    ((__half2*)&gxL[ti][0])[2 * qout] = __floats2half2_rn(acc.x, acc.y);
                    ((__half2*)&gxL[ti][0])[2 * qout + 1] = __floats2half2_rn(acc.z, acc.w);
                } else {
                    int jq = r - 96, j = jq >> 5, qi = jq & 31;
                    int nj = (3 * bp + j) >> 6;
                    const float* v = xC[1 + j][ti];
#pragma unroll 8
                    for (int k = 0; k < 128; ++k) {
                        float4 w = Wx4[nj * 4096 + k * 32 + qi];
                        float xv = v[k];
                        acc.x += w.x * xv; acc.y += w.y * xv;
                        acc.z += w.z * xv; acc.w += w.w * xv;
                    }
                    int cq = j * 32 + qi;
                    ((__half2*)&axL[ti][0])[2 * cq] = __floats2half2_rn(acc.x, acc.y);
                    ((__half2*)&axL[ti][0])[2 * cq + 1] = __floats2half2_rn(acc.z, acc.w);
                }
            }
            __syncthreads();
        }

        if (tid < 384) {
            float4 acc = {0.f, 0.f, 0.f, 0.f};
            if (tid < 192) {
                int q = tid % 96, ks = tid / 96;
                dotq<WS>(wWr, q, 96, hS, ks * 64, 64, acc);
            } else {
                int t2 = tid - 192;
                int jq = t2 % 96, ks = t2 / 96;
                int j = jq >> 5, qi = jq & 31;
                int nj = (3 * bp + j) >> 6;
                dotq<WS>(wWh, nj * 4096 + qi, 32, sS + j * 128, ks * 64, 64, acc);
            }
            *(float4*)&part1[tid][0] = acc;
        }
        __syncthreads();

        if (tid < 192) {
            if (tid < 96) {
                int q = tid;
                float4 a0 = *(float4*)&part1[q][0];
                float4 a1 = *(float4*)&part1[q + 96][0];
                float2 g0 = h2f2(((const u32*)&gxL[tt][0])[2 * q]);
                float2 g1 = h2f2(((const u32*)&gxL[tt][0])[2 * q + 1]);
                float4 r;
                r.x = a0.x + a1.x + g0.x + biasL[4 * q];
                r.y = a0.y + a1.y + g0.y + biasL[4 * q + 1];
                r.z = a0.z + a1.z + g1.x + biasL[4 * q + 2];
                r.w = a0.w + a1.w + g1.y + biasL[4 * q + 3];
                *(float4*)&gS[4 * q] = r;
            } else {
                int cq = tid - 96;
                float4 a0 = *(float4*)&part1[192 + cq][0];
                float4 a1 = *(float4*)&part1[288 + cq][0];
                float2 g0 = h2f2(((const u32*)&axL[tt][0])[2 * cq]);
                float2 g1 = h2f2(((const u32*)&axL[tt][0])[2 * cq + 1]);
                float4 r;
                r.x = a0.x + a1.x + g0.x;
                r.y = a0.y + a1.y + g0.y;
                r.z = a0.z + a1.z + g1.x;
                r.w = a0.w + a1.w + g1.y;
                *(float4*)&aS[4 * cq] = r;
            }
        }
        __syncthreads();

        if (tid < 192) {
            int q = tid % 96, ks = tid / 96;
            int j = q >> 5, qi = q & 31;
            int nj = (3 * bp + j) >> 6;
            float4 acc = {0.f, 0.f, 0.f, 0.f};
            dotq<WS>(wDw, nj * 4096 + qi, 32, aS + j * 128, ks * 64, 64, acc);
            *(float4*)&part2[tid][0] = acc;
        } else if (tid >= 384) {
            int u = tid - 384;
            float gi = sigf(gS[u]);
            float gf = sigf(gS[128 + u]);
            float gc = sigf(gS[256 + u]);
            float cn = gf * cS[u] + gi * tanh_(gc);
            cS[u] = cn;
            tcS[u] = tanh_(cn);
        }
        __syncthreads();

        if (tid < 96) {
            int j = tid >> 5, o = (tid & 31) * 4;
            float4 a0 = *(float4*)&part2[tid][0];
            float4 a1 = *(float4*)&part2[tid + 96][0];
            float4 r;
            r.x = fmaxf(a0.x + a1.x + DbL[j][o], 0.f);
            r.y = fmaxf(a0.y + a1.y + DbL[j][o + 1], 0.f);
            r.z = fmaxf(a0.z + a1.z + DbL[j][o + 2], 0.f);
            r.w = fmaxf(a0.w + a1.w + DbL[j][o + 3], 0.f);
            *(float4*)&pS[4 * tid] = r;
        }
        __syncthreads();

        if (tid < 256) {
            int q = tid & 31, ks = tid >> 5;
            float4 acc = {0.f, 0.f, 0.f, 0.f};
            dotq<WS>(wAw, q, 32, pS, ks * 48, 48, acc);
            *(float4*)&part3[tid][0] = acc;
        } else if (tid < 384) {
            int e = tid - 256;
#pragma unroll
            for (int j = 0; j < 3; ++j) {
                int q = j * 128 + e;
                sS[q] = stkj[j][0][e] * pS[q] + stkj[j][1][e] * sS[q];
            }
        }
        __syncthreads();

        if (tid < 128) {
            int u = tid;
            float y = AbL[u];
#pragma unroll
            for (int ks = 0; ks < 8; ++ks) y += part3[ks * 32 + (u >> 2)][u & 3];
            float hn = sigf(y) * tcS[u];
            hS[u] = hn;
            outp[((size_t)bp * TT + t) * 128 + u] = hn;
        }
        __syncthreads();
    }
}

extern "C" void kernel_launch(void* const* d_in, const int* in_sizes, int n_in,
                              void* d_out, int out_size, void* d_ws, size_t ws_size,
                              hipStream_t stream) {
    const float* x    = (const float*)d_in[0];
    const float* Wk   = (const float*)d_in[1];
    const float* Wr   = (const float*)d_in[2];
    const float* bias = (const float*)d_in[3];
    const float* Wx   = (const float*)d_in[4];
    const float* Wh   = (const float*)d_in[5];
    const float* stk  = (const float*)d_in[6];
    const float* Dw   = (const float*)d_in[7];
    const float* Db   = (const float*)d_in[8];
    const float* Aw   = (const float*)d_in[9];
    const float* Ab   = (const float*)d_in[10];
    float* outp = (float*)d_out;

    const size_t needW  = 196608 * sizeof(__half);  // 393,216 B (fp16 weights)
    const size_t needW2 = needW + (size_t)BB * TT * 768 * sizeof(__half);  // +201.3MB gax
    if (ws_size >= needW2) {
        __half* wt = (__half*)d_ws;
        __half* gax = wt + 196608;
        convert_w<<<dim3(384), dim3(512), 0, stream>>>(Wr, Wh, Dw, Aw, wt);
        gax_pre<<<dim3(BB, 64), dim3(384), 0, stream>>>(x, Wk, Wx, gax);
        tkan2<<<dim3(BB), dim3(512), 0, stream>>>(bias, stk, Db, Ab, wt, outp);
    } else if (ws_size >= needW) {
        __half* wt = (__half*)d_ws;
        convert_w<<<dim3(384), dim3(512), 0, stream>>>(Wr, Wh, Dw, Aw, wt);
        tkan<true><<<dim3(BB), dim3(512), 0, stream>>>(
            x, Wk, Wr, bias, Wx, Wh, stk, Dw, Db, Aw, Ab, wt, outp);
    } else {
        tkan<false><<<dim3(BB), dim3(512), 0, stream>>>(
            x, Wk, Wr, bias, Wx, Wh, stk, Dw, Db, Aw, Ab, (const __half*)nullptr,
            outp);
    }
}